// Round 1
// baseline (190.704 us; speedup 1.0000x reference)
//
#include <hip/hip_runtime.h>
#include <hip/hip_bf16.h>
#include <math.h>

// Shapes (fixed by the reference)
#define B_SZ   256
#define L_SZ   512
#define FD_SZ  64
#define H1_SZ  512
#define H2_SZ  512
#define G_SZ   32
#define DH_SZ  256
#define M_SZ   (B_SZ * L_SZ)   // 131072 rows

typedef __bf16 bfx8 __attribute__((ext_vector_type(8)));
typedef __bf16 bfx4 __attribute__((ext_vector_type(4)));
typedef float  f32x4 __attribute__((ext_vector_type(4)));

__device__ __forceinline__ float gelu_f(float x) {
  // exact gelu: x * 0.5 * (1 + erf(x / sqrt(2)))
  return 0.5f * x * (1.0f + erff(x * 0.70710678118654752440f));
}
__device__ __forceinline__ float softplus_f(float x) {
  return (x > 20.0f) ? x : log1pf(expf(x));
}
__device__ __forceinline__ __bf16 f2bf(float f) { return (__bf16)f; }

#define MFMA16(a, b, c) __builtin_amdgcn_mfma_f32_16x16x32_bf16((a), (b), (c), 0, 0, 0)

// ---------------------------------------------------------------------------
// Repack W1 (64x512) and W2 (512x512) fp32 -> bf16 MFMA fragment order.
// B-fragment (and transposed-A) layout for 16x16x32: lane l holds
// W[kbase + (l>>4)*8 + j][16*nb + (l&15)], j=0..7, stored as contiguous
// bf16x8 per lane -> 16B coalesced loads in the GEMM.
// W1p block id = mb*2 + ks (mb: H1/16, ks: FD/32). W2p block id = nb*16 + ks.
// ---------------------------------------------------------------------------
__global__ void repack_kernel(const float* __restrict__ W1,
                              const float* __restrict__ W2,
                              __bf16* __restrict__ W1p,
                              __bf16* __restrict__ W2p) {
  int t = blockIdx.x * 256 + threadIdx.x;
  if (t < 4096) {  // W1: 64 blocks * 64 lanes
    int lane = t & 63, blk = t >> 6;
    int ks = blk & 1, mb = blk >> 1;
    int col = 16 * mb + (lane & 15);
    int kbase = ks * 32 + (lane >> 4) * 8;
    bfx8 o;
#pragma unroll
    for (int j = 0; j < 8; ++j) o[j] = f2bf(W1[(size_t)(kbase + j) * H1_SZ + col]);
    *reinterpret_cast<bfx8*>(W1p + (size_t)t * 8) = o;
  } else if (t < 4096 + 32768) {  // W2: 512 blocks * 64 lanes
    int t2 = t - 4096;
    int lane = t2 & 63, blk = t2 >> 6;
    int ks = blk & 15, nb = blk >> 4;
    int col = 16 * nb + (lane & 15);
    int kbase = ks * 32 + (lane >> 4) * 8;
    bfx8 o;
#pragma unroll
    for (int j = 0; j < 8; ++j) o[j] = f2bf(W2[(size_t)(kbase + j) * H2_SZ + col]);
    *reinterpret_cast<bfx8*>(W2p + (size_t)t2 * 8) = o;
  }
}

// ---------------------------------------------------------------------------
// Fused MLP kernel: 64 rows per workgroup, 256 threads (4 waves).
//  GEMM1 (transposed: h1^T = W1^T * X^T) -> gelu -> h1 (bf16, LDS, k-major)
//  GEMM2 (h1 * W2) -> gelu -> reductions only (absorb/atten/pooled)
// ---------------------------------------------------------------------------
__global__ __launch_bounds__(256, 2) void fused_kernel(
    const float* __restrict__ Xl,
    const __bf16* __restrict__ W1p, const __bf16* __restrict__ W2p,
    const float* __restrict__ b1, const float* __restrict__ b2,
    const float* __restrict__ wa, const float* __restrict__ ba,
    const float* __restrict__ wt, const float* __restrict__ bt,
    float* __restrict__ absorbW, float* __restrict__ attenW,
    float* __restrict__ pooled) {
  __shared__ __bf16 Xs[64 * 64];      // 8 KB, row-major, 16B-chunk XOR swizzle
  __shared__ __bf16 H1s[64 * 512];    // 64 KB, [row][k] bf16, chunk XOR swizzle
  __shared__ float absorb_l[64];
  __shared__ float atten_l[64];

  const int tid = threadIdx.x;
  const int lane = tid & 63;
  const int w = tid >> 6;        // wave 0..3
  const int g = lane >> 4;       // k-group 0..3
  const int c = lane & 15;       // row/col within fragment
  const int R0 = blockIdx.x * 64;
  const int bidx = R0 >> 9;      // batch index (512 rows per b, tiles aligned)

  if (tid < 64) { absorb_l[tid] = 0.0f; atten_l[tid] = 0.0f; }

  // ---- stage Xl tile (64x64 fp32 -> bf16 LDS, swizzled) ----
#pragma unroll
  for (int i = 0; i < 4; ++i) {
    int idx = i * 256 + tid;      // float4 unit 0..1023
    int r = idx >> 4;
    int c4 = idx & 15;            // 16 float4 per row
    float4 v = *reinterpret_cast<const float4*>(Xl + (size_t)(R0 + r) * FD_SZ + c4 * 4);
    bfx4 bv;
    bv[0] = f2bf(v.x); bv[1] = f2bf(v.y); bv[2] = f2bf(v.z); bv[3] = f2bf(v.w);
    int chunk = c4 >> 1;          // 8-elem (16B) chunk 0..7
    int off = r * 64 + (((chunk ^ (r & 7)) << 3) + (c4 & 1) * 4);
    *reinterpret_cast<bfx4*>(&Xs[off]) = bv;
  }
  __syncthreads();

  // ---- GEMM1 (transposed): per wave 128 h1-cols (mb = 8w..8w+7), all 64 rows
  f32x4 acc1[8][4];
#pragma unroll
  for (int mi = 0; mi < 8; ++mi)
#pragma unroll
    for (int ni = 0; ni < 4; ++ni) acc1[mi][ni] = (f32x4){0.f, 0.f, 0.f, 0.f};

#pragma unroll
  for (int ks = 0; ks < 2; ++ks) {
    bfx8 a1[8];
#pragma unroll
    for (int mi = 0; mi < 8; ++mi) {
      int mb = w * 8 + mi;
      a1[mi] = *reinterpret_cast<const bfx8*>(W1p + ((size_t)(mb * 2 + ks) * 64 + lane) * 8);
    }
    bfx8 bx[4];
#pragma unroll
    for (int ni = 0; ni < 4; ++ni) {
      int r = 16 * ni + c;
      int chunk = ks * 4 + g;
      bx[ni] = *reinterpret_cast<const bfx8*>(&Xs[r * 64 + ((chunk ^ (r & 7)) << 3)]);
    }
#pragma unroll
    for (int mi = 0; mi < 8; ++mi)
#pragma unroll
      for (int ni = 0; ni < 4; ++ni)
        acc1[mi][ni] = MFMA16(a1[mi], bx[ni], acc1[mi][ni]);
  }

  // epilogue GEMM1: bias + gelu -> bf16 -> H1s[row][k] (k = 16*mb + 4*g + reg)
#pragma unroll
  for (int mi = 0; mi < 8; ++mi) {
    int mb = w * 8 + mi;
    float4 bias4 = *reinterpret_cast<const float4*>(b1 + 16 * mb + 4 * g);
#pragma unroll
    for (int ni = 0; ni < 4; ++ni) {
      int r = 16 * ni + c;                 // x-row (0..63)
      bfx4 pv;
      pv[0] = f2bf(gelu_f(acc1[mi][ni][0] + bias4.x));
      pv[1] = f2bf(gelu_f(acc1[mi][ni][1] + bias4.y));
      pv[2] = f2bf(gelu_f(acc1[mi][ni][2] + bias4.z));
      pv[3] = f2bf(gelu_f(acc1[mi][ni][3] + bias4.w));
      int kchunk = 2 * mb + (g >> 1);      // (16*mb + 4*g)/8
      int off = r * 512 + ((kchunk ^ (r & 7)) << 3) + (g & 1) * 4;
      *reinterpret_cast<bfx4*>(&H1s[off]) = pv;
    }
  }
  __syncthreads();

  // ---- GEMM2: per wave 128 h2-cols (nb = 8w..8w+7), rows 0..63, K = 512 ----
  f32x4 acc2[4][8];
#pragma unroll
  for (int m = 0; m < 4; ++m)
#pragma unroll
    for (int ni = 0; ni < 8; ++ni) acc2[m][ni] = (f32x4){0.f, 0.f, 0.f, 0.f};

  for (int ks = 0; ks < 16; ++ks) {
    bfx8 a2[4];
#pragma unroll
    for (int m = 0; m < 4; ++m) {
      int r = 16 * m + c;
      int chunk = 4 * ks + g;
      a2[m] = *reinterpret_cast<const bfx8*>(&H1s[r * 512 + ((chunk ^ (r & 7)) << 3)]);
    }
    bfx8 bw[8];
#pragma unroll
    for (int ni = 0; ni < 8; ++ni) {
      int nb = w * 8 + ni;
      bw[ni] = *reinterpret_cast<const bfx8*>(W2p + ((size_t)(nb * 16 + ks) * 64 + lane) * 8);
    }
#pragma unroll
    for (int ni = 0; ni < 8; ++ni)
#pragma unroll
      for (int m = 0; m < 4; ++m)
        acc2[m][ni] = MFMA16(a2[m], bw[ni], acc2[m][ni]);
  }

  // ---- epilogue GEMM2: bias+gelu, reduce to absorb/atten/pooled ----
  float b2v[8], wav[8], wtv[8];
#pragma unroll
  for (int ni = 0; ni < 8; ++ni) {
    int col = 16 * (w * 8 + ni) + c;
    b2v[ni] = b2[col];
    wav[ni] = wa[col];
    wtv[ni] = wt[col];
  }
  float pool[8];
#pragma unroll
  for (int ni = 0; ni < 8; ++ni) pool[ni] = 0.0f;

#pragma unroll
  for (int m = 0; m < 4; ++m) {
#pragma unroll
    for (int reg = 0; reg < 4; ++reg) {
      float sa = 0.0f, st = 0.0f;
#pragma unroll
      for (int ni = 0; ni < 8; ++ni) {
        float v = gelu_f(acc2[m][ni][reg] + b2v[ni]);
        sa += v * wav[ni];
        st += v * wtv[ni];
        pool[ni] += v;
      }
#pragma unroll
      for (int off = 1; off < 16; off <<= 1) {
        sa += __shfl_xor(sa, off, 64);
        st += __shfl_xor(st, off, 64);
      }
      if (c == 0) {
        int row = 16 * m + 4 * g + reg;
        atomicAdd(&absorb_l[row], sa);
        atomicAdd(&atten_l[row], st);
      }
    }
  }
#pragma unroll
  for (int ni = 0; ni < 8; ++ni) {
    float v = pool[ni];
    v += __shfl_xor(v, 16, 64);
    v += __shfl_xor(v, 32, 64);
    if (g == 0) atomicAdd(&pooled[bidx * H2_SZ + 16 * (w * 8 + ni) + c], v);
  }
  __syncthreads();

  if (tid < 64) {
    absorbW[R0 + tid] = softplus_f(absorb_l[tid] + ba[0]);
    attenW[R0 + tid]  = softplus_f(atten_l[tid] + bt[0]);
  }
}

// ---------------------------------------------------------------------------
// Finalize: per-b reversed exclusive-cumsum scan + captured, pooled head, out
// ---------------------------------------------------------------------------
__global__ __launch_bounds__(256) void finalize_kernel(
    const float* __restrict__ Xg,
    const float* __restrict__ absorbW, const float* __restrict__ attenW,
    const float* __restrict__ pooled,
    const float* __restrict__ Wd1, const float* __restrict__ bd1,
    const float* __restrict__ Wd2, const float* __restrict__ bd2,
    float* __restrict__ out) {
  __shared__ float s0[512];
  __shared__ float s1[512];
  __shared__ float sab[512];
  __shared__ float zz[544];
  __shared__ float redc[4];
  __shared__ float redd[4];

  const int b = blockIdx.x;
  const int t = threadIdx.x;
  const int i0 = t, i1 = t + 256;

  // load time-reversed absorb/atten
  float a0 = attenW[b * L_SZ + (L_SZ - 1 - i0)];
  float a1 = attenW[b * L_SZ + (L_SZ - 1 - i1)];
  sab[i0] = absorbW[b * L_SZ + (L_SZ - 1 - i0)];
  sab[i1] = absorbW[b * L_SZ + (L_SZ - 1 - i1)];
  s0[i0] = a0; s0[i1] = a1;
  __syncthreads();

  // Hillis-Steele inclusive scan (ping-pong)
  float* src = s0;
  float* dst = s1;
  for (int off = 1; off < 512; off <<= 1) {
    float v0 = src[i0] + ((i0 >= off) ? src[i0 - off] : 0.0f);
    float v1 = src[i1] + ((i1 >= off) ? src[i1 - off] : 0.0f);
    dst[i0] = v0; dst[i1] = v1;
    __syncthreads();
    float* tmp = src; src = dst; dst = tmp;
  }

  // captured partials: exp(-(incl - a)) * absorb_tb
  float p = expf(-(src[i0] - a0)) * sab[i0] + expf(-(src[i1] - a1)) * sab[i1];
#pragma unroll
  for (int off = 32; off; off >>= 1) p += __shfl_down(p, off, 64);
  if ((t & 63) == 0) redc[t >> 6] = p;

  // z = [Xg, pooled/L]
  if (t < G_SZ) zz[t] = Xg[b * G_SZ + t];
  zz[G_SZ + i0] = pooled[b * H2_SZ + i0] * (1.0f / (float)L_SZ);
  zz[G_SZ + i1] = pooled[b * H2_SZ + i1] * (1.0f / (float)L_SZ);
  __syncthreads();

  // d1[j] = gelu(z . Wd1[:,j] + bd1[j]);  v = d1[j] * Wd2[j]
  float s = bd1[t];
  for (int cc = 0; cc < G_SZ + H2_SZ; ++cc) s = fmaf(zz[cc], Wd1[cc * DH_SZ + t], s);
  float v = gelu_f(s) * Wd2[t];
#pragma unroll
  for (int off = 32; off; off >>= 1) v += __shfl_down(v, off, 64);
  if ((t & 63) == 0) redd[t >> 6] = v;
  __syncthreads();

  if (t == 0) {
    float captured = redc[0] + redc[1] + redc[2] + redc[3];
    float d = redd[0] + redd[1] + redd[2] + redd[3] + bd2[0];
    out[b] = captured + d;
  }
}

// ---------------------------------------------------------------------------
extern "C" void kernel_launch(void* const* d_in, const int* in_sizes, int n_in,
                              void* d_out, int out_size, void* d_ws, size_t ws_size,
                              hipStream_t stream) {
  const float* Xg  = (const float*)d_in[0];
  const float* Xl  = (const float*)d_in[1];
  const float* W1  = (const float*)d_in[2];
  const float* b1  = (const float*)d_in[3];
  const float* W2  = (const float*)d_in[4];
  const float* b2  = (const float*)d_in[5];
  const float* wa  = (const float*)d_in[6];
  const float* ba  = (const float*)d_in[7];
  const float* wt  = (const float*)d_in[8];
  const float* bt  = (const float*)d_in[9];
  const float* Wd1 = (const float*)d_in[10];
  const float* bd1 = (const float*)d_in[11];
  const float* Wd2 = (const float*)d_in[12];
  const float* bd2 = (const float*)d_in[13];

  char* ws = (char*)d_ws;
  __bf16* W1p    = (__bf16*)(ws + 0);            //  65536 B
  __bf16* W2p    = (__bf16*)(ws + 65536);        // 524288 B
  float* absorbW = (float*)(ws + 589824);        // 524288 B
  float* attenW  = (float*)(ws + 1114112);       // 524288 B
  float* pooled  = (float*)(ws + 1638400);       // 524288 B  (end 2162688)

  hipMemsetAsync(pooled, 0, B_SZ * H2_SZ * sizeof(float), stream);
  repack_kernel<<<144, 256, 0, stream>>>(W1, W2, W1p, W2p);
  fused_kernel<<<M_SZ / 64, 256, 0, stream>>>(Xl, W1p, W2p, b1, b2, wa, ba, wt, bt,
                                              absorbW, attenW, pooled);
  finalize_kernel<<<B_SZ, 256, 0, stream>>>(Xg, absorbW, attenW, pooled,
                                            Wd1, bd1, Wd2, bd2, (float*)d_out);
}

// Round 2
// 145.153 us; speedup vs baseline: 1.3138x; 1.3138x over previous
//
#include <hip/hip_runtime.h>
#include <hip/hip_bf16.h>
#include <math.h>

// Shapes (fixed by the reference)
#define B_SZ   256
#define L_SZ   512
#define FD_SZ  64
#define H1_SZ  512
#define H2_SZ  512
#define G_SZ   32
#define DH_SZ  256
#define M_SZ   (B_SZ * L_SZ)   // 131072 rows

typedef __bf16 bfx8 __attribute__((ext_vector_type(8)));
typedef __bf16 bfx4 __attribute__((ext_vector_type(4)));
typedef float  f32x4 __attribute__((ext_vector_type(4)));

__device__ __forceinline__ float gelu_exact(float x) {
  return 0.5f * x * (1.0f + erff(x * 0.70710678118654752440f));
}
// tanh-form gelu: x * sigmoid(1.5957691x + 0.0713548x^3). |err| <~ 5e-4.
__device__ __forceinline__ float gelu_fast(float x) {
  float x2 = x * x;
  float v = x * fmaf(0.0713548163f, x2, 1.5957691216f);
  float e = __expf(-v);                       // v_exp_f32 path, inf-safe
  return x * __builtin_amdgcn_rcpf(1.0f + e); // 1+inf -> inf -> rcp -> 0
}
__device__ __forceinline__ float softplus_f(float x) {
  return (x > 20.0f) ? x : log1pf(expf(x));
}
__device__ __forceinline__ __bf16 f2bf(float f) { return (__bf16)f; }

// DPP-based lane XOR for offsets 1 and 2 (quad_perm) — VALU pipe, not LDS.
__device__ __forceinline__ float dpp_xor1(float x) {
  int r = __builtin_amdgcn_mov_dpp(__builtin_bit_cast(int, x), 0xB1, 0xF, 0xF, true);
  return __builtin_bit_cast(float, r);
}
__device__ __forceinline__ float dpp_xor2(float x) {
  int r = __builtin_amdgcn_mov_dpp(__builtin_bit_cast(int, x), 0x4E, 0xF, 0xF, true);
  return __builtin_bit_cast(float, r);
}

#define MFMA16(a, b, c) __builtin_amdgcn_mfma_f32_16x16x32_bf16((a), (b), (c), 0, 0, 0)

// ---------------------------------------------------------------------------
// Repack W1 (64x512) and W2 (512x512) fp32 -> bf16 MFMA fragment order.
// Lane l of block holds W[kbase + (l>>4)*8 + j][16*nb + (l&15)], j=0..7.
// W1p block id = mb*2 + ks (mb: H1/16, ks: FD/32). W2p block id = nb*16 + ks.
// ---------------------------------------------------------------------------
__global__ void repack_kernel(const float* __restrict__ W1,
                              const float* __restrict__ W2,
                              __bf16* __restrict__ W1p,
                              __bf16* __restrict__ W2p) {
  int t = blockIdx.x * 256 + threadIdx.x;
  if (t < 4096) {  // W1: 64 blocks * 64 lanes
    int lane = t & 63, blk = t >> 6;
    int ks = blk & 1, mb = blk >> 1;
    int col = 16 * mb + (lane & 15);
    int kbase = ks * 32 + (lane >> 4) * 8;
    bfx8 o;
#pragma unroll
    for (int j = 0; j < 8; ++j) o[j] = f2bf(W1[(size_t)(kbase + j) * H1_SZ + col]);
    *reinterpret_cast<bfx8*>(W1p + (size_t)t * 8) = o;
  } else if (t < 4096 + 32768) {  // W2: 512 blocks * 64 lanes
    int t2 = t - 4096;
    int lane = t2 & 63, blk = t2 >> 6;
    int ks = blk & 15, nb = blk >> 4;
    int col = 16 * nb + (lane & 15);
    int kbase = ks * 32 + (lane >> 4) * 8;
    bfx8 o;
#pragma unroll
    for (int j = 0; j < 8; ++j) o[j] = f2bf(W2[(size_t)(kbase + j) * H2_SZ + col]);
    *reinterpret_cast<bfx8*>(W2p + (size_t)t2 * 8) = o;
  }
}

// ---------------------------------------------------------------------------
// Fused MLP kernel: 64 rows per workgroup, 512 threads (8 waves).
// Wave w owns 64 h-columns (mb/nb = 4w..4w+3).
//  GEMM1 (transposed: h1^T = W1^T * X^T, X direct from global) -> gelu -> H1s
//  GEMM2 (h1 * W2) -> gelu -> reductions (absorb/atten/pooled)
// ---------------------------------------------------------------------------
__global__ __launch_bounds__(512, 4) void fused_kernel(
    const float* __restrict__ Xl,
    const __bf16* __restrict__ W1p, const __bf16* __restrict__ W2p,
    const float* __restrict__ b1, const float* __restrict__ b2,
    const float* __restrict__ wa, const float* __restrict__ ba,
    const float* __restrict__ wt, const float* __restrict__ bt,
    float* __restrict__ absorbW, float* __restrict__ attenW,
    float* __restrict__ pooled) {
  __shared__ __bf16 H1s[64 * 512];    // 64 KB, [row][k] bf16, chunk XOR swizzle
  __shared__ float absorb_l[64];
  __shared__ float atten_l[64];

  const int tid = threadIdx.x;
  const int lane = tid & 63;
  const int w = tid >> 6;        // wave 0..7
  const int g = lane >> 4;       // k-group 0..3
  const int c = lane & 15;       // row/col within fragment
  const int R0 = blockIdx.x * 64;
  const int bidx = R0 >> 9;      // batch index (tiles aligned within batch)

  if (tid < 64) { absorb_l[tid] = 0.0f; atten_l[tid] = 0.0f; }

  // ---- GEMM1 (transposed): wave computes h1 cols 16*(4w)..16*(4w+3)+15 ----
  f32x4 acc1[4][4];
#pragma unroll
  for (int mi = 0; mi < 4; ++mi)
#pragma unroll
    for (int ni = 0; ni < 4; ++ni) acc1[mi][ni] = (f32x4){0.f, 0.f, 0.f, 0.f};

#pragma unroll
  for (int ks = 0; ks < 2; ++ks) {
    bfx8 a1[4];
#pragma unroll
    for (int mi = 0; mi < 4; ++mi) {
      int mb = 4 * w + mi;
      a1[mi] = *reinterpret_cast<const bfx8*>(W1p + ((size_t)(mb * 2 + ks) * 64 + lane) * 8);
    }
    bfx8 bx[4];
#pragma unroll
    for (int ni = 0; ni < 4; ++ni) {
      // lane needs X[R0 + 16*ni + c][32*ks + 8*g + j], j=0..7 (contiguous fp32)
      const float* xp = Xl + (size_t)(R0 + 16 * ni + c) * FD_SZ + 32 * ks + 8 * g;
      float4 u0 = *reinterpret_cast<const float4*>(xp);
      float4 u1 = *reinterpret_cast<const float4*>(xp + 4);
      bfx8 bv;
      bv[0] = f2bf(u0.x); bv[1] = f2bf(u0.y); bv[2] = f2bf(u0.z); bv[3] = f2bf(u0.w);
      bv[4] = f2bf(u1.x); bv[5] = f2bf(u1.y); bv[6] = f2bf(u1.z); bv[7] = f2bf(u1.w);
      bx[ni] = bv;
    }
#pragma unroll
    for (int mi = 0; mi < 4; ++mi)
#pragma unroll
      for (int ni = 0; ni < 4; ++ni)
        acc1[mi][ni] = MFMA16(a1[mi], bx[ni], acc1[mi][ni]);
  }

  // epilogue GEMM1: bias + gelu -> bf16 -> H1s[row][k] (k = 16*mb + 4*g + reg)
#pragma unroll
  for (int mi = 0; mi < 4; ++mi) {
    int mb = 4 * w + mi;
    float4 bias4 = *reinterpret_cast<const float4*>(b1 + 16 * mb + 4 * g);
#pragma unroll
    for (int ni = 0; ni < 4; ++ni) {
      int r = 16 * ni + c;                 // x-row (0..63)
      bfx4 pv;
      pv[0] = f2bf(gelu_fast(acc1[mi][ni][0] + bias4.x));
      pv[1] = f2bf(gelu_fast(acc1[mi][ni][1] + bias4.y));
      pv[2] = f2bf(gelu_fast(acc1[mi][ni][2] + bias4.z));
      pv[3] = f2bf(gelu_fast(acc1[mi][ni][3] + bias4.w));
      int kchunk = 2 * mb + (g >> 1);      // (16*mb + 4*g)/8
      int off = r * 512 + ((kchunk ^ (r & 7)) << 3) + (g & 1) * 4;
      *reinterpret_cast<bfx4*>(&H1s[off]) = pv;
    }
  }
  __syncthreads();

  // ---- GEMM2: wave computes h2 cols 16*(4w)..16*(4w+3)+15, rows 0..63 ------
  f32x4 acc2[4][4];
#pragma unroll
  for (int m = 0; m < 4; ++m)
#pragma unroll
    for (int ni = 0; ni < 4; ++ni) acc2[m][ni] = (f32x4){0.f, 0.f, 0.f, 0.f};

  for (int ks = 0; ks < 16; ++ks) {
    bfx8 a2[4];
#pragma unroll
    for (int m = 0; m < 4; ++m) {
      int r = 16 * m + c;
      int chunk = 4 * ks + g;
      a2[m] = *reinterpret_cast<const bfx8*>(&H1s[r * 512 + ((chunk ^ (r & 7)) << 3)]);
    }
    bfx8 bw[4];
#pragma unroll
    for (int ni = 0; ni < 4; ++ni) {
      int nb = 4 * w + ni;
      bw[ni] = *reinterpret_cast<const bfx8*>(W2p + ((size_t)(nb * 16 + ks) * 64 + lane) * 8);
    }
#pragma unroll
    for (int ni = 0; ni < 4; ++ni)
#pragma unroll
      for (int m = 0; m < 4; ++m)
        acc2[m][ni] = MFMA16(a2[m], bw[ni], acc2[m][ni]);
  }

  // ---- epilogue GEMM2: bias+gelu, reduce to absorb/atten/pooled ----
  float b2v[4], wav[4], wtv[4];
#pragma unroll
  for (int ni = 0; ni < 4; ++ni) {
    int col = 16 * (4 * w + ni) + c;
    b2v[ni] = b2[col];
    wav[ni] = wa[col];
    wtv[ni] = wt[col];
  }
  float pool[4];
#pragma unroll
  for (int ni = 0; ni < 4; ++ni) pool[ni] = 0.0f;

#pragma unroll
  for (int m = 0; m < 4; ++m) {
#pragma unroll
    for (int reg = 0; reg < 4; ++reg) {
      float sa = 0.0f, st = 0.0f;
#pragma unroll
      for (int ni = 0; ni < 4; ++ni) {
        float v = gelu_fast(acc2[m][ni][reg] + b2v[ni]);
        sa += v * wav[ni];
        st += v * wtv[ni];
        pool[ni] += v;
      }
      // reduce across c (16 lanes): xor1/xor2 on VALU (DPP), xor4/8 via shfl
      sa += dpp_xor1(sa);  st += dpp_xor1(st);
      sa += dpp_xor2(sa);  st += dpp_xor2(st);
      sa += __shfl_xor(sa, 4, 64);  st += __shfl_xor(st, 4, 64);
      sa += __shfl_xor(sa, 8, 64);  st += __shfl_xor(st, 8, 64);
      if (c == 0) {
        int row = 16 * m + 4 * g + reg;
        atomicAdd(&absorb_l[row], sa);
        atomicAdd(&atten_l[row], st);
      }
    }
  }
#pragma unroll
  for (int ni = 0; ni < 4; ++ni) {
    float v = pool[ni];
    v += __shfl_xor(v, 16, 64);
    v += __shfl_xor(v, 32, 64);
    if (g == 0) atomicAdd(&pooled[bidx * H2_SZ + 16 * (4 * w + ni) + c], v);
  }
  __syncthreads();

  if (tid < 64) {
    absorbW[R0 + tid] = softplus_f(absorb_l[tid] + ba[0]);
    attenW[R0 + tid]  = softplus_f(atten_l[tid] + bt[0]);
  }
}

// ---------------------------------------------------------------------------
// Finalize: per-b reversed exclusive-cumsum scan + captured, pooled head, out
// ---------------------------------------------------------------------------
__global__ __launch_bounds__(256) void finalize_kernel(
    const float* __restrict__ Xg,
    const float* __restrict__ absorbW, const float* __restrict__ attenW,
    const float* __restrict__ pooled,
    const float* __restrict__ Wd1, const float* __restrict__ bd1,
    const float* __restrict__ Wd2, const float* __restrict__ bd2,
    float* __restrict__ out) {
  __shared__ float s0[512];
  __shared__ float s1[512];
  __shared__ float sab[512];
  __shared__ float zz[544];
  __shared__ float redc[4];
  __shared__ float redd[4];

  const int b = blockIdx.x;
  const int t = threadIdx.x;
  const int i0 = t, i1 = t + 256;

  // load time-reversed absorb/atten
  float a0 = attenW[b * L_SZ + (L_SZ - 1 - i0)];
  float a1 = attenW[b * L_SZ + (L_SZ - 1 - i1)];
  sab[i0] = absorbW[b * L_SZ + (L_SZ - 1 - i0)];
  sab[i1] = absorbW[b * L_SZ + (L_SZ - 1 - i1)];
  s0[i0] = a0; s0[i1] = a1;
  __syncthreads();

  // Hillis-Steele inclusive scan (ping-pong)
  float* src = s0;
  float* dst = s1;
  for (int off = 1; off < 512; off <<= 1) {
    float v0 = src[i0] + ((i0 >= off) ? src[i0 - off] : 0.0f);
    float v1 = src[i1] + ((i1 >= off) ? src[i1 - off] : 0.0f);
    dst[i0] = v0; dst[i1] = v1;
    __syncthreads();
    float* tmp = src; src = dst; dst = tmp;
  }

  // captured partials: exp(-(incl - a)) * absorb_tb
  float p = expf(-(src[i0] - a0)) * sab[i0] + expf(-(src[i1] - a1)) * sab[i1];
#pragma unroll
  for (int off = 32; off; off >>= 1) p += __shfl_down(p, off, 64);
  if ((t & 63) == 0) redc[t >> 6] = p;

  // z = [Xg, pooled/L]
  if (t < G_SZ) zz[t] = Xg[b * G_SZ + t];
  zz[G_SZ + i0] = pooled[b * H2_SZ + i0] * (1.0f / (float)L_SZ);
  zz[G_SZ + i1] = pooled[b * H2_SZ + i1] * (1.0f / (float)L_SZ);
  __syncthreads();

  // d1[j] = gelu(z . Wd1[:,j] + bd1[j]);  v = d1[j] * Wd2[j]
  float s = bd1[t];
  for (int cc = 0; cc < G_SZ + H2_SZ; ++cc) s = fmaf(zz[cc], Wd1[cc * DH_SZ + t], s);
  float v = gelu_exact(s) * Wd2[t];
#pragma unroll
  for (int off = 32; off; off >>= 1) v += __shfl_down(v, off, 64);
  if ((t & 63) == 0) redd[t >> 6] = v;
  __syncthreads();

  if (t == 0) {
    float captured = redc[0] + redc[1] + redc[2] + redc[3];
    float d = redd[0] + redd[1] + redd[2] + redd[3] + bd2[0];
    out[b] = captured + d;
  }
}

// ---------------------------------------------------------------------------
extern "C" void kernel_launch(void* const* d_in, const int* in_sizes, int n_in,
                              void* d_out, int out_size, void* d_ws, size_t ws_size,
                              hipStream_t stream) {
  const float* Xg  = (const float*)d_in[0];
  const float* Xl  = (const float*)d_in[1];
  const float* W1  = (const float*)d_in[2];
  const float* b1  = (const float*)d_in[3];
  const float* W2  = (const float*)d_in[4];
  const float* b2  = (const float*)d_in[5];
  const float* wa  = (const float*)d_in[6];
  const float* ba  = (const float*)d_in[7];
  const float* wt  = (const float*)d_in[8];
  const float* bt  = (const float*)d_in[9];
  const float* Wd1 = (const float*)d_in[10];
  const float* bd1 = (const float*)d_in[11];
  const float* Wd2 = (const float*)d_in[12];
  const float* bd2 = (const float*)d_in[13];

  char* ws = (char*)d_ws;
  __bf16* W1p    = (__bf16*)(ws + 0);            //  65536 B
  __bf16* W2p    = (__bf16*)(ws + 65536);        // 524288 B
  float* absorbW = (float*)(ws + 589824);        // 524288 B
  float* attenW  = (float*)(ws + 1114112);       // 524288 B
  float* pooled  = (float*)(ws + 1638400);       // 524288 B  (end 2162688)

  hipMemsetAsync(pooled, 0, B_SZ * H2_SZ * sizeof(float), stream);
  repack_kernel<<<144, 256, 0, stream>>>(W1, W2, W1p, W2p);
  fused_kernel<<<M_SZ / 64, 512, 0, stream>>>(Xl, W1p, W2p, b1, b2, wa, ba, wt, bt,
                                              absorbW, attenW, pooled);
  finalize_kernel<<<B_SZ, 256, 0, stream>>>(Xg, absorbW, attenW, pooled,
                                            Wd1, bd1, Wd2, bd2, (float*)d_out);
}